// Round 1
// baseline (198.494 us; speedup 1.0000x reference)
//
#include <hip/hip_runtime.h>

// Problem constants (from setup_inputs): B=32, H=W=1024, N=96 boxes/batch.
#define BATCH 32
#define HDIM 1024
#define WDIM 1024
#define NBOX 96
#define ROWS_PER_BLOCK 16
#define THREADS 256

// ---------------------------------------------------------------------------
// Kernel 0: zero the per-box accumulators in workspace (ws is poisoned 0xAA).
// ---------------------------------------------------------------------------
__global__ void zero_ws_kernel(float* __restrict__ ws) {
    int i = blockIdx.x * blockDim.x + threadIdx.x;
    if (i < BATCH * NBOX) ws[i] = 0.0f;
}

// ---------------------------------------------------------------------------
// Kernel 1: per-row prefix sums; accumulate per-box partial sums.
// Grid: (BATCH * HDIM / ROWS_PER_BLOCK) blocks of 256 threads.
// Each block owns ROWS_PER_BLOCK consecutive rows of one batch image.
// box_sum(b,n) = sum over rows i in [y1,y2) of (P_i[x2] - P_i[x1])
// where P_i is the exclusive row prefix. We store the INCLUSIVE prefix
// (aligned float4 -> conflict-free ds_write_b128) and read P[x] as
// (x>0 ? Pinc[x-1] : 0).
// ---------------------------------------------------------------------------
__global__ __launch_bounds__(THREADS) void box_accum_kernel(
    const float* __restrict__ img,
    const int* __restrict__ bboxes,
    float* __restrict__ ws_box) {

    __shared__ float Pinc[WDIM];       // inclusive row prefix (4 KB)
    __shared__ float wave_tot[THREADS / 64];

    const int t = threadIdx.x;
    const int lane = t & 63;
    const int wave = t >> 6;

    const int blocks_per_batch = HDIM / ROWS_PER_BLOCK;   // 64
    const int b = blockIdx.x / blocks_per_batch;
    const int row0 = (blockIdx.x % blocks_per_batch) * ROWS_PER_BLOCK;

    // Box params: thread n < NBOX owns box n of this batch.
    int x1 = 0, y1 = 0, x2 = 0, y2 = 0;
    const bool owns_box = (t < NBOX);
    if (owns_box) {
        const int4 bb = ((const int4*)bboxes)[b * NBOX + t];
        x1 = min(max(bb.x, 0), WDIM);
        y1 = min(max(bb.y, 0), WDIM);
        x2 = min(max(bb.z, 0), WDIM);
        y2 = min(max(bb.w, 0), WDIM);
    }
    const bool x_valid = owns_box && (x2 > x1);   // implies x2 >= 1
    float acc = 0.0f;

    const float* rowbase = img + ((size_t)b * HDIM + row0) * WDIM;

    for (int r = 0; r < ROWS_PER_BLOCK; ++r) {
        // --- load 4 contiguous floats per thread (coalesced 4 KB/row) ---
        float4 v = ((const float4*)(rowbase + (size_t)r * WDIM))[t];

        // sequential prefix of the 4 elements
        float s0 = v.x;
        float s1 = s0 + v.y;
        float s2 = s1 + v.z;
        float s3 = s2 + v.w;

        // wave-inclusive scan of per-thread totals (64 lanes)
        float wscan = s3;
        #pragma unroll
        for (int off = 1; off < 64; off <<= 1) {
            float u = __shfl_up(wscan, off, 64);
            if (lane >= off) wscan += u;
        }
        float excl_in_wave = wscan - s3;
        if (lane == 63) wave_tot[wave] = wscan;
        __syncthreads();

        float wave_base = 0.0f;
        #pragma unroll
        for (int w = 0; w < THREADS / 64; ++w)
            wave_base += (w < wave) ? wave_tot[w] : 0.0f;

        float base = wave_base + excl_in_wave;  // exclusive prefix at elem 4t

        // inclusive prefix, aligned float4 store -> ds_write_b128, no conflicts
        float4 pv;
        pv.x = base + s0;
        pv.y = base + s1;
        pv.z = base + s2;
        pv.w = base + s3;
        ((float4*)Pinc)[t] = pv;
        __syncthreads();

        // --- box accumulation for this row ---
        const int i = row0 + r;
        if (x_valid && (y1 <= i) && (i < y2)) {
            float right = Pinc[x2 - 1];                       // x2 >= 1
            float left  = (x1 > 0) ? Pinc[x1 - 1] : 0.0f;
            acc += right - left;
        }
        __syncthreads();   // protect Pinc/wave_tot before next iteration
    }

    if (owns_box && acc != 0.0f) {
        atomicAdd(&ws_box[b * NBOX + t], acc);
    }
}

// ---------------------------------------------------------------------------
// Kernel 2: loss = sum over boxes of relu(1 - (valid ? box_sum : 0)).
// Single block; ~3072 boxes.
// ---------------------------------------------------------------------------
__global__ void finalize_kernel(const float* __restrict__ ws_box,
                                const int* __restrict__ bboxes,
                                float* __restrict__ out) {
    __shared__ float red[THREADS / 64];
    const int t = threadIdx.x;
    float local = 0.0f;
    for (int idx = t; idx < BATCH * NBOX; idx += THREADS) {
        const int4 bb = ((const int4*)bboxes)[idx];
        int x1 = min(max(bb.x, 0), WDIM);
        int y1 = min(max(bb.y, 0), WDIM);
        int x2 = min(max(bb.z, 0), WDIM);
        int y2 = min(max(bb.w, 0), WDIM);
        bool valid = (x2 > x1) && (y2 > y1);
        float s = valid ? ws_box[idx] : 0.0f;
        local += fmaxf(1.0f - s, 0.0f);
    }
    #pragma unroll
    for (int off = 32; off > 0; off >>= 1)
        local += __shfl_down(local, off, 64);
    if ((t & 63) == 0) red[t >> 6] = local;
    __syncthreads();
    if (t == 0) {
        float r = 0.0f;
        #pragma unroll
        for (int w = 0; w < THREADS / 64; ++w) r += red[w];
        out[0] = r;
    }
}

// ---------------------------------------------------------------------------
extern "C" void kernel_launch(void* const* d_in, const int* in_sizes, int n_in,
                              void* d_out, int out_size, void* d_ws, size_t ws_size,
                              hipStream_t stream) {
    const float* img    = (const float*)d_in[0];   // (32,1,1024,1024) fp32
    const int*   bboxes = (const int*)d_in[1];     // (32,96,4) int32
    float* out = (float*)d_out;                    // scalar
    float* ws_box = (float*)d_ws;                  // BATCH*NBOX accumulators

    zero_ws_kernel<<<(BATCH * NBOX + THREADS - 1) / THREADS, THREADS, 0, stream>>>(ws_box);

    const int nblocks = BATCH * HDIM / ROWS_PER_BLOCK;   // 2048
    box_accum_kernel<<<nblocks, THREADS, 0, stream>>>(img, bboxes, ws_box);

    finalize_kernel<<<1, THREADS, 0, stream>>>(ws_box, bboxes, out);
}